// Round 6
// baseline (284.986 us; speedup 1.0000x reference)
//
#include <hip/hip_runtime.h>

typedef unsigned short u16;
typedef unsigned char u8;
typedef short s16x8 __attribute__((ext_vector_type(8)));
typedef unsigned short u16x4 __attribute__((ext_vector_type(4)));
typedef float f32x4 __attribute__((ext_vector_type(4)));
typedef int i32x4 __attribute__((ext_vector_type(4)));
typedef int i32x8 __attribute__((ext_vector_type(8)));

#define AS1 __attribute__((address_space(1)))
#define AS3 __attribute__((address_space(3)))

// async global->LDS, 16B per lane; LDS dest = wave-uniform base + lane*16
__device__ __forceinline__ void g2l16(const void* g, void* l) {
  __builtin_amdgcn_global_load_lds((const AS1 void*)g, (AS3 void*)l, 16, 0, 0);
}

__device__ __forceinline__ float b2f(u16 u) {
  union { unsigned int i; float f; } x; x.i = ((unsigned int)u) << 16; return x.f;
}
__device__ __forceinline__ u16 f2b(float f) {  // round-to-nearest-even
  unsigned int u = __builtin_bit_cast(unsigned int, f);
  return (u16)((u + 0x7fffu + ((u >> 16) & 1u)) >> 16);
}
__device__ __forceinline__ u8 f2e4m3(float v) {
  int p = __builtin_amdgcn_cvt_pk_fp8_f32(v, 0.f, 0, false);
  return (u8)(p & 0xff);
}
__device__ __forceinline__ float sigm(float x) { return 1.f / (1.f + __expf(-x)); }
__device__ __forceinline__ float tanh_f(float x) { return 2.f / (1.f + __expf(-2.f * x)) - 1.f; }

// dims: T=48 N=4096 F_IN=H1=F_OUT=64; TH = 3072

// ---------------- kpre: adj->fp8 + weight prep + k1 (XHT), one launch ----------------
// blocks [0,4096): adj fp32->fp8 e4m3 scaled x4096 (coalesced)
// blocks [4096,4144): wct;  [4144,4147): lbt;  [4147,5683): XHT tiles
__global__ __launch_bounds__(256) void kpre(
    const float* __restrict__ a, u8* __restrict__ ab,
    const float* __restrict__ fcw, const float* __restrict__ fcb,
    const float* __restrict__ x, u8* __restrict__ xht,
    const float* __restrict__ Wz, const float* __restrict__ Wr, const float* __restrict__ Wh,
    const float* __restrict__ Lz, const float* __restrict__ Lr, const float* __restrict__ Lh,
    u16* __restrict__ wct, u16* __restrict__ lbt) {
  int b = blockIdx.x, tid = threadIdx.x;
  if (b < 4096) {
    size_t idx = (size_t)b * 256 + tid;   // lane-contiguous float4 index
    const float4* src = (const float4*)a;
    unsigned int* dst = (unsigned int*)ab;
#pragma unroll
    for (int k = 0; k < 4; ++k) {
      float4 v = src[idx + (size_t)k * 1048576];
      unsigned int p = __builtin_amdgcn_cvt_pk_fp8_f32(v.x * 4096.f, v.y * 4096.f, 0, false);
      p = __builtin_amdgcn_cvt_pk_fp8_f32(v.z * 4096.f, v.w * 4096.f, p, true);
      dst[idx + (size_t)k * 1048576] = p;
    }
    return;
  }
  if (b < 4144) {
    int idx = (b - 4096) * 256 + tid;  // 0..12287
    int c_cat = idx >> 6, hh = idx & 63;
    int g = c_cat >> 6, c = c_cat & 63;
    const float* W = (g == 0) ? Wz : (g == 1) ? Wr : Wh;
    const float* L = (g == 0) ? Lz : (g == 1) ? Lr : Lh;
    float acc = 0.f;
    for (int m = 0; m < 64; ++m) acc += W[hh * 64 + m] * L[m * 64 + c];
    wct[c_cat * 64 + hh] = f2b(acc);
    return;
  }
  if (b < 4147) {
    int g = b - 4144;
    const float* L = (g == 0) ? Lz : (g == 1) ? Lr : Lh;
    for (int i = 0; i < 16; ++i) {
      int idx = tid * 16 + i; int c = idx >> 6, hh = idx & 63;
      lbt[g * 4096 + c * 64 + hh] = f2b(L[(64 + hh) * 64 + c]);
    }
    return;
  }
  // ---- XHT part: kb in [0,1536): t = kb>>5, n0 = (kb&31)*128 ----
  int kb = b - 4147;
  int t = kb >> 5, n0 = (kb & 31) * 128;
  __shared__ __align__(16) u16 xs[128 * 72];   // padded: 2-way banks
  __shared__ __align__(16) u16 fw[64 * 72];
  __shared__ __align__(16) u8 xh8[64 * 128];   // [h][node]
  __shared__ float fb[64];
  int w = tid >> 6, l = tid & 63;
#pragma unroll
  for (int i = 0; i < 16; ++i) {       // fw[h][f] = fc_w[f][h], coalesced fp32 reads
    int idx = tid + i * 256;
    int h = idx & 63, f = idx >> 6;
    fw[h * 72 + f] = f2b(fcw[f * 64 + h]);
  }
  const float4* xg = (const float4*)(x + ((size_t)t * 4096 + n0) * 64);
#pragma unroll
  for (int i = 0; i < 8; ++i) {
    int f = tid + i * 256;             // lane-contiguous float4 index
    float4 v = xg[f];
    u16x4 p; p[0] = f2b(v.x); p[1] = f2b(v.y); p[2] = f2b(v.z); p[3] = f2b(v.w);
    *(u16x4*)&xs[(f >> 4) * 72 + (f & 15) * 4] = p;
  }
  if (tid < 64) fb[tid] = fcb[tid];
  __syncthreads();

  int lm = l & 15, q = l >> 4;
  f32x4 acc[4][2];
#pragma unroll
  for (int i = 0; i < 4; ++i)
#pragma unroll
    for (int j = 0; j < 2; ++j)
#pragma unroll
      for (int r = 0; r < 4; ++r) acc[i][j][r] = 0.f;
#pragma unroll
  for (int s = 0; s < 2; ++s) {
    s16x8 af[4], bf[2];
#pragma unroll
    for (int i = 0; i < 4; ++i) af[i] = *(const s16x8*)&fw[(16 * i + lm) * 72 + 32 * s + q * 8];
#pragma unroll
    for (int j = 0; j < 2; ++j) bf[j] = *(const s16x8*)&xs[(32 * w + 16 * j + lm) * 72 + 32 * s + q * 8];
#pragma unroll
    for (int i = 0; i < 4; ++i)
#pragma unroll
      for (int j = 0; j < 2; ++j)
        acc[i][j] = __builtin_amdgcn_mfma_f32_16x16x32_bf16(af[i], bf[j], acc[i][j], 0, 0, 0);
  }
#pragma unroll
  for (int i = 0; i < 4; ++i)
#pragma unroll
    for (int j = 0; j < 2; ++j) {
      int node = 32 * w + 16 * j + lm;
      int h0 = 16 * i + q * 4;
#pragma unroll
      for (int r = 0; r < 4; ++r) {
        float v = acc[i][j][r] + fb[h0 + r];
        xh8[(h0 + r) * 128 + node] = f2e4m3(v > 0.f ? v : 0.f);
      }
    }
  __syncthreads();
  {
    int h = tid >> 2, seg = tid & 3;   // 32 bytes per thread
    u8* dst = xht + (size_t)(t * 64 + h) * 4096 + n0 + seg * 32;
    const u8* src = &xh8[h * 128 + seg * 32];
    *(i32x4*)dst = *(const i32x4*)src;
    *(i32x4*)(dst + 16) = *(const i32x4*)(src + 16);
  }
}

// ---------------- k2: M = adj8 @ XH8, MX fp8 K=128, 128x192 tile ----------------
// r4 variant (best measured): both operands g2l16-staged with rotation
// swizzle, double-buffered (2 x 40KB), ONE __syncthreads per K-step.
// r0/r4/r5 all ~60us: k2 is LDS-pipe-throughput bound in this geometry,
// not sync-structure bound.
__global__ __launch_bounds__(256) void k2(
    const u8* __restrict__ A, const u8* __restrict__ B, u16* __restrict__ M) {
  __shared__ __align__(16) u8 sh[81920];   // 2 x (A 16KB + B 24KB)
  int tid = threadIdx.x, w = tid >> 6, l = tid & 63;
  int nt = blockIdx.x, mt = blockIdx.y;
  const u8* Ab = A + (size_t)mt * 128 * 4096;
  const u8* Bb = B + (size_t)nt * 192 * 4096;
  int lm = l & 15, q = l >> 4;
  int wm = w >> 1, wn = w & 1;
  int srow = l >> 3, scol = l & 7;
  f32x4 acc[4][6];
#pragma unroll
  for (int i = 0; i < 4; ++i)
#pragma unroll
    for (int j = 0; j < 6; ++j)
#pragma unroll
      for (int r = 0; r < 4; ++r) acc[i][j][r] = 0.f;

#define STAGE(bsel, kk)                                                       \
  do {                                                                        \
    u8* As_ = sh + (bsel) * 40960;                                            \
    u8* Bs_ = As_ + 16384;                                                    \
    _Pragma("unroll") for (int j = 0; j < 4; ++j) {   /* A: 32 rows/wave */   \
      int r0 = 32 * w + 8 * j;                                                \
      int row = r0 + srow;                                                    \
      int c = (scol - row) & 7;                                               \
      g2l16(Ab + (size_t)row * 4096 + (kk) + c * 16, As_ + r0 * 128);         \
    }                                                                         \
    _Pragma("unroll") for (int j = 0; j < 6; ++j) {   /* B: 48 rows/wave */   \
      int r0 = 48 * w + 8 * j;                                                \
      int row = r0 + srow;                                                    \
      int c = (scol - row) & 7;                                               \
      g2l16(Bb + (size_t)row * 4096 + (kk) + c * 16, Bs_ + r0 * 128);         \
    }                                                                         \
  } while (0)

  STAGE(0, 0);
  __syncthreads();                     // buf0 ready

  for (int it = 0; it < 32; ++it) {
    int k0b = it * 128;
    int cur = it & 1;
    if (it < 31) STAGE(cur ^ 1, k0b + 128);   // prefetch next K-tile into other buffer
    const u8* As = sh + cur * 40960;
    const u8* Bs = As + 16384;
    i32x8 a8[4];
#pragma unroll
    for (int i = 0; i < 4; ++i) {
      int ra = 64 * wm + 16 * i + lm;
      int p0 = (2 * q + ra) & 7, p1 = (2 * q + 1 + ra) & 7;
      i32x4 lo = *(const i32x4*)&As[ra * 128 + p0 * 16];
      i32x4 hi = *(const i32x4*)&As[ra * 128 + p1 * 16];
      a8[i] = __builtin_shufflevector(lo, hi, 0, 1, 2, 3, 4, 5, 6, 7);
    }
#pragma unroll
    for (int j = 0; j < 6; ++j) {
      int rb = 96 * wn + 16 * j + lm;
      int q0 = (2 * q + rb) & 7, q1 = (2 * q + 1 + rb) & 7;
      i32x4 lo2 = *(const i32x4*)&Bs[rb * 128 + q0 * 16];
      i32x4 hi2 = *(const i32x4*)&Bs[rb * 128 + q1 * 16];
      i32x8 b8 = __builtin_shufflevector(lo2, hi2, 0, 1, 2, 3, 4, 5, 6, 7);
#pragma unroll
      for (int i = 0; i < 4; ++i)
        acc[i][j] = __builtin_amdgcn_mfma_scale_f32_16x16x128_f8f6f4(
            a8[i], b8, acc[i][j], 0, 0, 0, 127, 0, 127);  // fmt=fp8, scale=2^0
    }
    __syncthreads();   // one barrier/iter: drains next-buf writes AND cur-buf reads
  }
#undef STAGE

  // epilogue: 2-pass transpose through LDS. tb = [64][200] u16 (25.6KB)
  u16* tb = (u16*)sh;
  const float sc = 1.f / 4096.f;
#pragma unroll
  for (int p = 0; p < 2; ++p) {
    if (p) __syncthreads();            // pass-0 LDS reads done before overwrite
    if (wm == p) {
#pragma unroll
      for (int i = 0; i < 4; ++i)
#pragma unroll
        for (int j = 0; j < 6; ++j)
#pragma unroll
          for (int r = 0; r < 4; ++r)
            tb[(16 * i + 4 * q + r) * 200 + 96 * wn + 16 * j + lm] = f2b(acc[i][j][r] * sc);
    }
    __syncthreads();
    int row = tid >> 2, seg = tid & 3;   // 64 rows x 384B; 96B (48 u16) per thread
    u16* dst = M + (size_t)(mt * 128 + p * 64 + row) * 3072 + nt * 192 + seg * 48;
    const u16* src = &tb[row * 200 + seg * 48];
#pragma unroll
    for (int v = 0; v < 6; ++v)
      *(i32x4*)(dst + 8 * v) = *(const i32x4*)(src + 8 * v);
  }
}

// ---------------- k3: GRU scan; 8 nodes/block, grid 512 = 2 blocks/CU ----------------
// k3 is a 48-step sequential chain (2 barriers + dependent MFMA chains +
// transcendentals per step) at 1 block/CU -> latency-bound with nothing
// co-resident. Split node dim 16->8 per block: lanes 8..15 duplicate lanes
// 0..7's node (lm&7), so the MFMA B-operand carries each node twice (all
// real data, self-consistent GRU feedback); only lm<8 stores. Two
// independent blocks per CU interleave their dependency stalls.
__global__ __launch_bounds__(256) void k3(
    const u16* __restrict__ M, const u16* __restrict__ wct, const u16* __restrict__ lbt,
    const float* __restrict__ bz, const float* __restrict__ br, const float* __restrict__ bh,
    float* __restrict__ out) {
  __shared__ __align__(16) u16 hhi[16 * 72], hlo[16 * 72];
  __shared__ __align__(16) u16 rhi[16 * 72], rlo[16 * 72];
  int tid = threadIdx.x, w = tid >> 6, l = tid & 63;
  int nb0 = blockIdx.x * 8;
  int lm = l & 15, q = l >> 4;
  int node = nb0 + (lm & 7);           // lanes 8..15 mirror lanes 0..7
  int cb = 16 * w + q * 4;
  s16x8 afw[3][2], afl[3][2];
#pragma unroll
  for (int g = 0; g < 3; ++g)
#pragma unroll
    for (int s = 0; s < 2; ++s) {
      afw[g][s] = *(const s16x8*)&wct[(size_t)(g * 64 + 16 * w + lm) * 64 + 32 * s + q * 8];
      afl[g][s] = *(const s16x8*)&lbt[(size_t)(g * 64 + 16 * w + lm) * 64 + 32 * s + q * 8];
    }
  for (int i = tid; i < 16 * 72; i += 256) { hhi[i] = 0; hlo[i] = 0; }
  f32x4 bzv, brv, bhv, hv;
#pragma unroll
  for (int r = 0; r < 4; ++r) {
    bzv[r] = bz[cb + r]; brv[r] = br[cb + r]; bhv[r] = bh[cb + r]; hv[r] = 0.f;
  }
  __syncthreads();

  const u16* Mrow = M + (size_t)node * 3072;
  s16x8 Mn[2];
  Mn[0] = *(const s16x8*)&Mrow[q * 8];
  Mn[1] = *(const s16x8*)&Mrow[32 + q * 8];

  for (int t = 0; t < 48; ++t) {
    s16x8 Mc[2] = {Mn[0], Mn[1]};
    if (t < 47) {
      Mn[0] = *(const s16x8*)&Mrow[(t + 1) * 64 + q * 8];
      Mn[1] = *(const s16x8*)&Mrow[(t + 1) * 64 + 32 + q * 8];
    }
    f32x4 uzw, uzh, urw, urh;
#pragma unroll
    for (int r = 0; r < 4; ++r) { uzw[r] = 0.f; uzh[r] = 0.f; urw[r] = 0.f; urh[r] = 0.f; }
#pragma unroll
    for (int s = 0; s < 2; ++s) {
      s16x8 hh = *(const s16x8*)&hhi[lm * 72 + 32 * s + q * 8];
      s16x8 hl = *(const s16x8*)&hlo[lm * 72 + 32 * s + q * 8];
      uzw = __builtin_amdgcn_mfma_f32_16x16x32_bf16(afw[0][s], Mc[s], uzw, 0, 0, 0);
      uzh = __builtin_amdgcn_mfma_f32_16x16x32_bf16(afl[0][s], hh, uzh, 0, 0, 0);
      uzh = __builtin_amdgcn_mfma_f32_16x16x32_bf16(afl[0][s], hl, uzh, 0, 0, 0);
      urw = __builtin_amdgcn_mfma_f32_16x16x32_bf16(afw[1][s], Mc[s], urw, 0, 0, 0);
      urh = __builtin_amdgcn_mfma_f32_16x16x32_bf16(afl[1][s], hh, urh, 0, 0, 0);
      urh = __builtin_amdgcn_mfma_f32_16x16x32_bf16(afl[1][s], hl, urh, 0, 0, 0);
    }
    f32x4 zv, rv;
#pragma unroll
    for (int r = 0; r < 4; ++r) {
      zv[r] = sigm(uzw[r] + uzh[r] + bzv[r]);
      rv[r] = sigm(urw[r] + urh[r] + brv[r]);
    }
    {
      u16x4 phi, plo;
#pragma unroll
      for (int r = 0; r < 4; ++r) {
        float p = hv[r] * rv[r];
        u16 hi = f2b(p); phi[r] = hi; plo[r] = f2b(p - b2f(hi));
      }
      *(u16x4*)&rhi[lm * 72 + cb] = phi;
      *(u16x4*)&rlo[lm * 72 + cb] = plo;
    }
    __syncthreads();                   // h*r visible; all reads of h done
    f32x4 uhw, uhh;
#pragma unroll
    for (int r = 0; r < 4; ++r) { uhw[r] = 0.f; uhh[r] = 0.f; }
#pragma unroll
    for (int s = 0; s < 2; ++s) {
      s16x8 rh = *(const s16x8*)&rhi[lm * 72 + 32 * s + q * 8];
      s16x8 rl = *(const s16x8*)&rlo[lm * 72 + 32 * s + q * 8];
      uhw = __builtin_amdgcn_mfma_f32_16x16x32_bf16(afw[2][s], Mc[s], uhw, 0, 0, 0);
      uhh = __builtin_amdgcn_mfma_f32_16x16x32_bf16(afl[2][s], rh, uhh, 0, 0, 0);
      uhh = __builtin_amdgcn_mfma_f32_16x16x32_bf16(afl[2][s], rl, uhh, 0, 0, 0);
    }
    {
      u16x4 phi, plo;
#pragma unroll
      for (int r = 0; r < 4; ++r) {
        float th = tanh_f(uhw[r] + uhh[r] + bhv[r]);
        float hn = zv[r] * hv[r] + (1.f - zv[r]) * th;
        hv[r] = hn;
        u16 hi = f2b(hn); phi[r] = hi; plo[r] = f2b(hn - b2f(hi));
      }
      *(u16x4*)&hhi[lm * 72 + cb] = phi;
      *(u16x4*)&hlo[lm * 72 + cb] = plo;
    }
    __syncthreads();                   // h_{t+1} visible; r-buffer reads done
  }
  if (lm < 8) {
#pragma unroll
    for (int r = 0; r < 4; ++r)
      out[(size_t)node * 64 + cb + r] = hv[r];
  }
}

extern "C" void kernel_launch(void* const* d_in, const int* in_sizes, int n_in,
                              void* d_out, int out_size, void* d_ws, size_t ws_size,
                              hipStream_t stream) {
  const float* x   = (const float*)d_in[0];
  const float* adj = (const float*)d_in[1];
  const float* fcw = (const float*)d_in[2];
  const float* fcb = (const float*)d_in[3];
  const float* Wz  = (const float*)d_in[4];
  const float* Wr  = (const float*)d_in[5];
  const float* Wh  = (const float*)d_in[6];
  const float* Lz  = (const float*)d_in[7];
  const float* Lr  = (const float*)d_in[8];
  const float* Lh  = (const float*)d_in[9];
  const float* bz  = (const float*)d_in[10];
  const float* br  = (const float*)d_in[11];
  const float* bh  = (const float*)d_in[12];
  char* ws = (char*)d_ws;
  // ws layout (bytes):
  u8*  xht  = (u8*)(ws);                           // [3072][4096] fp8: 12,582,912
  u8*  adj8 = (u8*)(ws + (size_t)12582912);        // [4096][4096] fp8: 16,777,216
  u16* Mm   = (u16*)(ws + (size_t)29360128);       // [4096][3072] bf16: 25,165,824
  u16* wct  = (u16*)(ws + (size_t)54525952);       // 24 KB
  u16* lbt  = (u16*)(ws + (size_t)54550528);       // 24 KB
  float* outp = (float*)d_out;

  hipLaunchKernelGGL(kpre, dim3(5683), dim3(256), 0, stream,
                     adj, adj8, fcw, fcb, x, xht, Wz, Wr, Wh, Lz, Lr, Lh, wct, lbt);
  hipLaunchKernelGGL(k2, dim3(16, 32), dim3(256), 0, stream, adj8, xht, Mm);
  hipLaunchKernelGGL(k3, dim3(512), dim3(256), 0, stream, Mm, wct, lbt, bz, br, bh, outp);
}

// Round 8
// 256.412 us; speedup vs baseline: 1.1114x; 1.1114x over previous
//
#include <hip/hip_runtime.h>

typedef unsigned short u16;
typedef unsigned char u8;
typedef short s16x8 __attribute__((ext_vector_type(8)));
typedef unsigned short u16x4 __attribute__((ext_vector_type(4)));
typedef float f32x4 __attribute__((ext_vector_type(4)));
typedef int i32x4 __attribute__((ext_vector_type(4)));
typedef int i32x8 __attribute__((ext_vector_type(8)));

#define AS1 __attribute__((address_space(1)))
#define AS3 __attribute__((address_space(3)))

// async global->LDS, 16B per lane; LDS dest = wave-uniform base + lane*16
__device__ __forceinline__ void g2l16(const void* g, void* l) {
  __builtin_amdgcn_global_load_lds((const AS1 void*)g, (AS3 void*)l, 16, 0, 0);
}

__device__ __forceinline__ float b2f(u16 u) {
  union { unsigned int i; float f; } x; x.i = ((unsigned int)u) << 16; return x.f;
}
__device__ __forceinline__ u16 f2b(float f) {  // round-to-nearest-even
  unsigned int u = __builtin_bit_cast(unsigned int, f);
  return (u16)((u + 0x7fffu + ((u >> 16) & 1u)) >> 16);
}
__device__ __forceinline__ u8 f2e4m3(float v) {
  int p = __builtin_amdgcn_cvt_pk_fp8_f32(v, 0.f, 0, false);
  return (u8)(p & 0xff);
}
__device__ __forceinline__ float sigm(float x) { return 1.f / (1.f + __expf(-x)); }
__device__ __forceinline__ float tanh_f(float x) { return 2.f / (1.f + __expf(-2.f * x)) - 1.f; }

// dims: T=48 N=4096 F_IN=H1=F_OUT=64; TH = 3072

// ---------------- kpre: adj->fp8 + weight prep + k1 (XHT), one launch ----------------
// blocks [0,4096): adj fp32->fp8 e4m3 scaled x4096 (coalesced)
// blocks [4096,4144): wct;  [4144,4147): lbt;  [4147,5683): XHT tiles
__global__ __launch_bounds__(256) void kpre(
    const float* __restrict__ a, u8* __restrict__ ab,
    const float* __restrict__ fcw, const float* __restrict__ fcb,
    const float* __restrict__ x, u8* __restrict__ xht,
    const float* __restrict__ Wz, const float* __restrict__ Wr, const float* __restrict__ Wh,
    const float* __restrict__ Lz, const float* __restrict__ Lr, const float* __restrict__ Lh,
    u16* __restrict__ wct, u16* __restrict__ lbt) {
  int b = blockIdx.x, tid = threadIdx.x;
  if (b < 4096) {
    size_t idx = (size_t)b * 256 + tid;   // lane-contiguous float4 index
    const float4* src = (const float4*)a;
    unsigned int* dst = (unsigned int*)ab;
#pragma unroll
    for (int k = 0; k < 4; ++k) {
      float4 v = src[idx + (size_t)k * 1048576];
      unsigned int p = __builtin_amdgcn_cvt_pk_fp8_f32(v.x * 4096.f, v.y * 4096.f, 0, false);
      p = __builtin_amdgcn_cvt_pk_fp8_f32(v.z * 4096.f, v.w * 4096.f, p, true);
      dst[idx + (size_t)k * 1048576] = p;
    }
    return;
  }
  if (b < 4144) {
    int idx = (b - 4096) * 256 + tid;  // 0..12287
    int c_cat = idx >> 6, hh = idx & 63;
    int g = c_cat >> 6, c = c_cat & 63;
    const float* W = (g == 0) ? Wz : (g == 1) ? Wr : Wh;
    const float* L = (g == 0) ? Lz : (g == 1) ? Lr : Lh;
    float acc = 0.f;
    for (int m = 0; m < 64; ++m) acc += W[hh * 64 + m] * L[m * 64 + c];
    wct[c_cat * 64 + hh] = f2b(acc);
    return;
  }
  if (b < 4147) {
    int g = b - 4144;
    const float* L = (g == 0) ? Lz : (g == 1) ? Lr : Lh;
    for (int i = 0; i < 16; ++i) {
      int idx = tid * 16 + i; int c = idx >> 6, hh = idx & 63;
      lbt[g * 4096 + c * 64 + hh] = f2b(L[(64 + hh) * 64 + c]);
    }
    return;
  }
  // ---- XHT part: kb in [0,1536): t = kb>>5, n0 = (kb&31)*128 ----
  int kb = b - 4147;
  int t = kb >> 5, n0 = (kb & 31) * 128;
  __shared__ __align__(16) u16 xs[128 * 72];   // padded: 2-way banks
  __shared__ __align__(16) u16 fw[64 * 72];
  __shared__ __align__(16) u8 xh8[64 * 128];   // [h][node]
  __shared__ float fb[64];
  int w = tid >> 6, l = tid & 63;
#pragma unroll
  for (int i = 0; i < 16; ++i) {       // fw[h][f] = fc_w[f][h], coalesced fp32 reads
    int idx = tid + i * 256;
    int h = idx & 63, f = idx >> 6;
    fw[h * 72 + f] = f2b(fcw[f * 64 + h]);
  }
  const float4* xg = (const float4*)(x + ((size_t)t * 4096 + n0) * 64);
#pragma unroll
  for (int i = 0; i < 8; ++i) {
    int f = tid + i * 256;             // lane-contiguous float4 index
    float4 v = xg[f];
    u16x4 p; p[0] = f2b(v.x); p[1] = f2b(v.y); p[2] = f2b(v.z); p[3] = f2b(v.w);
    *(u16x4*)&xs[(f >> 4) * 72 + (f & 15) * 4] = p;
  }
  if (tid < 64) fb[tid] = fcb[tid];
  __syncthreads();

  int lm = l & 15, q = l >> 4;
  f32x4 acc[4][2];
#pragma unroll
  for (int i = 0; i < 4; ++i)
#pragma unroll
    for (int j = 0; j < 2; ++j)
#pragma unroll
      for (int r = 0; r < 4; ++r) acc[i][j][r] = 0.f;
#pragma unroll
  for (int s = 0; s < 2; ++s) {
    s16x8 af[4], bf[2];
#pragma unroll
    for (int i = 0; i < 4; ++i) af[i] = *(const s16x8*)&fw[(16 * i + lm) * 72 + 32 * s + q * 8];
#pragma unroll
    for (int j = 0; j < 2; ++j) bf[j] = *(const s16x8*)&xs[(32 * w + 16 * j + lm) * 72 + 32 * s + q * 8];
#pragma unroll
    for (int i = 0; i < 4; ++i)
#pragma unroll
      for (int j = 0; j < 2; ++j)
        acc[i][j] = __builtin_amdgcn_mfma_f32_16x16x32_bf16(af[i], bf[j], acc[i][j], 0, 0, 0);
  }
#pragma unroll
  for (int i = 0; i < 4; ++i)
#pragma unroll
    for (int j = 0; j < 2; ++j) {
      int node = 32 * w + 16 * j + lm;
      int h0 = 16 * i + q * 4;
#pragma unroll
      for (int r = 0; r < 4; ++r) {
        float v = acc[i][j][r] + fb[h0 + r];
        xh8[(h0 + r) * 128 + node] = f2e4m3(v > 0.f ? v : 0.f);
      }
    }
  __syncthreads();
  {
    int h = tid >> 2, seg = tid & 3;   // 32 bytes per thread
    u8* dst = xht + (size_t)(t * 64 + h) * 4096 + n0 + seg * 32;
    const u8* src = &xh8[h * 128 + seg * 32];
    *(i32x4*)dst = *(const i32x4*)src;
    *(i32x4*)(dst + 16) = *(const i32x4*)(src + 16);
  }
}

// ---------------- k2: M = adj8 @ XH8, MX fp8 K=128, 128x192 tile ----------------
// r4 variant (best measured): both operands g2l16-staged with rotation
// swizzle, double-buffered (2 x 40KB), ONE __syncthreads per K-step.
__global__ __launch_bounds__(256) void k2(
    const u8* __restrict__ A, const u8* __restrict__ B, u16* __restrict__ M) {
  __shared__ __align__(16) u8 sh[81920];   // 2 x (A 16KB + B 24KB)
  int tid = threadIdx.x, w = tid >> 6, l = tid & 63;
  int nt = blockIdx.x, mt = blockIdx.y;
  const u8* Ab = A + (size_t)mt * 128 * 4096;
  const u8* Bb = B + (size_t)nt * 192 * 4096;
  int lm = l & 15, q = l >> 4;
  int wm = w >> 1, wn = w & 1;
  int srow = l >> 3, scol = l & 7;
  f32x4 acc[4][6];
#pragma unroll
  for (int i = 0; i < 4; ++i)
#pragma unroll
    for (int j = 0; j < 6; ++j)
#pragma unroll
      for (int r = 0; r < 4; ++r) acc[i][j][r] = 0.f;

#define STAGE(bsel, kk)                                                       \
  do {                                                                        \
    u8* As_ = sh + (bsel) * 40960;                                            \
    u8* Bs_ = As_ + 16384;                                                    \
    _Pragma("unroll") for (int j = 0; j < 4; ++j) {   /* A: 32 rows/wave */   \
      int r0 = 32 * w + 8 * j;                                                \
      int row = r0 + srow;                                                    \
      int c = (scol - row) & 7;                                               \
      g2l16(Ab + (size_t)row * 4096 + (kk) + c * 16, As_ + r0 * 128);         \
    }                                                                         \
    _Pragma("unroll") for (int j = 0; j < 6; ++j) {   /* B: 48 rows/wave */   \
      int r0 = 48 * w + 8 * j;                                                \
      int row = r0 + srow;                                                    \
      int c = (scol - row) & 7;                                               \
      g2l16(Bb + (size_t)row * 4096 + (kk) + c * 16, Bs_ + r0 * 128);         \
    }                                                                         \
  } while (0)

  STAGE(0, 0);
  __syncthreads();                     // buf0 ready

  for (int it = 0; it < 32; ++it) {
    int k0b = it * 128;
    int cur = it & 1;
    if (it < 31) STAGE(cur ^ 1, k0b + 128);   // prefetch next K-tile into other buffer
    const u8* As = sh + cur * 40960;
    const u8* Bs = As + 16384;
    i32x8 a8[4];
#pragma unroll
    for (int i = 0; i < 4; ++i) {
      int ra = 64 * wm + 16 * i + lm;
      int p0 = (2 * q + ra) & 7, p1 = (2 * q + 1 + ra) & 7;
      i32x4 lo = *(const i32x4*)&As[ra * 128 + p0 * 16];
      i32x4 hi = *(const i32x4*)&As[ra * 128 + p1 * 16];
      a8[i] = __builtin_shufflevector(lo, hi, 0, 1, 2, 3, 4, 5, 6, 7);
    }
#pragma unroll
    for (int j = 0; j < 6; ++j) {
      int rb = 96 * wn + 16 * j + lm;
      int q0 = (2 * q + rb) & 7, q1 = (2 * q + 1 + rb) & 7;
      i32x4 lo2 = *(const i32x4*)&Bs[rb * 128 + q0 * 16];
      i32x4 hi2 = *(const i32x4*)&Bs[rb * 128 + q1 * 16];
      i32x8 b8 = __builtin_shufflevector(lo2, hi2, 0, 1, 2, 3, 4, 5, 6, 7);
#pragma unroll
      for (int i = 0; i < 4; ++i)
        acc[i][j] = __builtin_amdgcn_mfma_scale_f32_16x16x128_f8f6f4(
            a8[i], b8, acc[i][j], 0, 0, 0, 127, 0, 127);  // fmt=fp8, scale=2^0
    }
    __syncthreads();   // one barrier/iter: drains next-buf writes AND cur-buf reads
  }
#undef STAGE

  // epilogue: 2-pass transpose through LDS. tb = [64][200] u16 (25.6KB)
  u16* tb = (u16*)sh;
  const float sc = 1.f / 4096.f;
#pragma unroll
  for (int p = 0; p < 2; ++p) {
    if (p) __syncthreads();            // pass-0 LDS reads done before overwrite
    if (wm == p) {
#pragma unroll
      for (int i = 0; i < 4; ++i)
#pragma unroll
        for (int j = 0; j < 6; ++j)
#pragma unroll
          for (int r = 0; r < 4; ++r)
            tb[(16 * i + 4 * q + r) * 200 + 96 * wn + 16 * j + lm] = f2b(acc[i][j][r] * sc);
    }
    __syncthreads();
    int row = tid >> 2, seg = tid & 3;   // 64 rows x 384B; 96B (48 u16) per thread
    u16* dst = M + (size_t)(mt * 128 + p * 64 + row) * 3072 + nt * 192 + seg * 48;
    const u16* src = &tb[row * 200 + seg * 48];
#pragma unroll
    for (int v = 0; v < 6; ++v)
      *(i32x4*)(dst + 8 * v) = *(const i32x4*)(src + 8 * v);
  }
}

// ---------------- k3: GRU scan; grid 256 (16 nodes/block, original work) ----------------
// Counter-driven rework (r6: VALUBusy 61%, 2.4M bank conflicts at this grid):
//  (a) h/r state in [16][64] u16 LDS with 16B-slot XOR swizzle (slot ^= lm&7)
//      -- likely ~neutral (8-touch/bank floor for 16B/lane reads of a 2KB
//      array exists in any layout) but correct/bijective.
//  (b) M-dependent MFMAs (uzw/urw/uhw) for step t+1 computed at END of step t,
//      seeded with the bias via the MFMA C operand: 6 MFMAs off the critical
//      path, zero per-step acc-init movs, no separate bias adds.
//  (c) h-chains depth 4 -> 2: hh chained on the ready M-part, hl on a shared
//      zero, joined by one f32x4 add.
__global__ __launch_bounds__(256) void k3(
    const u16* __restrict__ M, const u16* __restrict__ wct, const u16* __restrict__ lbt,
    const float* __restrict__ bz, const float* __restrict__ br, const float* __restrict__ bh,
    float* __restrict__ out) {
  __shared__ __align__(16) u16 hhi[1024], hlo[1024];   // [16 rows][64], slot-swizzled
  __shared__ __align__(16) u16 rhi[1024], rlo[1024];
  int tid = threadIdx.x, w = tid >> 6, l = tid & 63;
  int nb0 = blockIdx.x * 16;
  int lm = l & 15, q = l >> 4;
  int am = lm & 7;
  int cb = 16 * w + q * 4;
  // swizzled u16 indices: read slot (4s+q)^am; write slot (2w+(q>>1))^am
  int rd0 = lm * 64 + ((q ^ am) * 8);            // s=0
  int rd1 = lm * 64 + (((4 + q) ^ am) * 8);      // s=1
  int wi  = lm * 64 + (((2 * w + (q >> 1)) ^ am) * 8) + 4 * (q & 1);
  s16x8 afw[3][2], afl[3][2];
#pragma unroll
  for (int g = 0; g < 3; ++g)
#pragma unroll
    for (int s = 0; s < 2; ++s) {
      afw[g][s] = *(const s16x8*)&wct[(size_t)(g * 64 + 16 * w + lm) * 64 + 32 * s + q * 8];
      afl[g][s] = *(const s16x8*)&lbt[(size_t)(g * 64 + 16 * w + lm) * 64 + 32 * s + q * 8];
    }
  for (int i = tid; i < 1024; i += 256) { hhi[i] = 0; hlo[i] = 0; }
  f32x4 bzv, brv, bhv, hv;
#pragma unroll
  for (int r = 0; r < 4; ++r) {
    bzv[r] = bz[cb + r]; brv[r] = br[cb + r]; bhv[r] = bh[cb + r]; hv[r] = 0.f;
  }
  const f32x4 zf = {0.f, 0.f, 0.f, 0.f};
  __syncthreads();

  const u16* Mrow = M + (size_t)(nb0 + lm) * 3072;
  s16x8 Mn[2];
  Mn[0] = *(const s16x8*)&Mrow[q * 8];
  Mn[1] = *(const s16x8*)&Mrow[32 + q * 8];
  // M-part + bias for t=0 (C operand = bias vector)
  f32x4 uzwC = __builtin_amdgcn_mfma_f32_16x16x32_bf16(afw[0][0], Mn[0], bzv, 0, 0, 0);
  uzwC = __builtin_amdgcn_mfma_f32_16x16x32_bf16(afw[0][1], Mn[1], uzwC, 0, 0, 0);
  f32x4 urwC = __builtin_amdgcn_mfma_f32_16x16x32_bf16(afw[1][0], Mn[0], brv, 0, 0, 0);
  urwC = __builtin_amdgcn_mfma_f32_16x16x32_bf16(afw[1][1], Mn[1], urwC, 0, 0, 0);
  f32x4 uhwC = __builtin_amdgcn_mfma_f32_16x16x32_bf16(afw[2][0], Mn[0], bhv, 0, 0, 0);
  uhwC = __builtin_amdgcn_mfma_f32_16x16x32_bf16(afw[2][1], Mn[1], uhwC, 0, 0, 0);

  for (int t = 0; t < 48; ++t) {
    if (t < 47) {                      // prefetch M column-block t+1
      Mn[0] = *(const s16x8*)&Mrow[(t + 1) * 64 + q * 8];
      Mn[1] = *(const s16x8*)&Mrow[(t + 1) * 64 + 32 + q * 8];
    }
    // ---- phase A: z, r gates ----
    s16x8 hh0 = *(const s16x8*)&hhi[rd0], hh1 = *(const s16x8*)&hhi[rd1];
    s16x8 hl0 = *(const s16x8*)&hlo[rd0], hl1 = *(const s16x8*)&hlo[rd1];
    f32x4 uzA = __builtin_amdgcn_mfma_f32_16x16x32_bf16(afl[0][0], hh0, uzwC, 0, 0, 0);
    uzA = __builtin_amdgcn_mfma_f32_16x16x32_bf16(afl[0][1], hh1, uzA, 0, 0, 0);
    f32x4 uzB = __builtin_amdgcn_mfma_f32_16x16x32_bf16(afl[0][0], hl0, zf, 0, 0, 0);
    uzB = __builtin_amdgcn_mfma_f32_16x16x32_bf16(afl[0][1], hl1, uzB, 0, 0, 0);
    f32x4 urA = __builtin_amdgcn_mfma_f32_16x16x32_bf16(afl[1][0], hh0, urwC, 0, 0, 0);
    urA = __builtin_amdgcn_mfma_f32_16x16x32_bf16(afl[1][1], hh1, urA, 0, 0, 0);
    f32x4 urB = __builtin_amdgcn_mfma_f32_16x16x32_bf16(afl[1][0], hl0, zf, 0, 0, 0);
    urB = __builtin_amdgcn_mfma_f32_16x16x32_bf16(afl[1][1], hl1, urB, 0, 0, 0);
    f32x4 zv, rv;
#pragma unroll
    for (int r = 0; r < 4; ++r) {
      zv[r] = sigm(uzA[r] + uzB[r]);
      rv[r] = sigm(urA[r] + urB[r]);
    }
    {
      u16x4 phi, plo;
#pragma unroll
      for (int r = 0; r < 4; ++r) {
        float p = hv[r] * rv[r];
        u16 hi = f2b(p); phi[r] = hi; plo[r] = f2b(p - b2f(hi));
      }
      *(u16x4*)&rhi[wi] = phi;
      *(u16x4*)&rlo[wi] = plo;
    }
    __syncthreads();                   // h*r visible; all reads of h done
    // ---- phase B: candidate + state update ----
    s16x8 rh0 = *(const s16x8*)&rhi[rd0], rh1 = *(const s16x8*)&rhi[rd1];
    s16x8 rl0 = *(const s16x8*)&rlo[rd0], rl1 = *(const s16x8*)&rlo[rd1];
    f32x4 uhA = __builtin_amdgcn_mfma_f32_16x16x32_bf16(afl[2][0], rh0, uhwC, 0, 0, 0);
    uhA = __builtin_amdgcn_mfma_f32_16x16x32_bf16(afl[2][1], rh1, uhA, 0, 0, 0);
    f32x4 uhB = __builtin_amdgcn_mfma_f32_16x16x32_bf16(afl[2][0], rl0, zf, 0, 0, 0);
    uhB = __builtin_amdgcn_mfma_f32_16x16x32_bf16(afl[2][1], rl1, uhB, 0, 0, 0);
    {
      u16x4 phi, plo;
#pragma unroll
      for (int r = 0; r < 4; ++r) {
        float th = tanh_f(uhA[r] + uhB[r]);
        float hn = zv[r] * hv[r] + (1.f - zv[r]) * th;
        hv[r] = hn;
        u16 hi = f2b(hn); phi[r] = hi; plo[r] = f2b(hn - b2f(hi));
      }
      *(u16x4*)&hhi[wi] = phi;
      *(u16x4*)&hlo[wi] = plo;
    }
    if (t < 47) {                      // next step's M-part (off critical path)
      uzwC = __builtin_amdgcn_mfma_f32_16x16x32_bf16(afw[0][0], Mn[0], bzv, 0, 0, 0);
      uzwC = __builtin_amdgcn_mfma_f32_16x16x32_bf16(afw[0][1], Mn[1], uzwC, 0, 0, 0);
      urwC = __builtin_amdgcn_mfma_f32_16x16x32_bf16(afw[1][0], Mn[0], brv, 0, 0, 0);
      urwC = __builtin_amdgcn_mfma_f32_16x16x32_bf16(afw[1][1], Mn[1], urwC, 0, 0, 0);
      uhwC = __builtin_amdgcn_mfma_f32_16x16x32_bf16(afw[2][0], Mn[0], bhv, 0, 0, 0);
      uhwC = __builtin_amdgcn_mfma_f32_16x16x32_bf16(afw[2][1], Mn[1], uhwC, 0, 0, 0);
    }
    __syncthreads();                   // h_{t+1} visible; r-buffer reads done
  }
#pragma unroll
  for (int r = 0; r < 4; ++r)
    out[(size_t)(nb0 + lm) * 64 + cb + r] = hv[r];
}

extern "C" void kernel_launch(void* const* d_in, const int* in_sizes, int n_in,
                              void* d_out, int out_size, void* d_ws, size_t ws_size,
                              hipStream_t stream) {
  const float* x   = (const float*)d_in[0];
  const float* adj = (const float*)d_in[1];
  const float* fcw = (const float*)d_in[2];
  const float* fcb = (const float*)d_in[3];
  const float* Wz  = (const float*)d_in[4];
  const float* Wr  = (const float*)d_in[5];
  const float* Wh  = (const float*)d_in[6];
  const float* Lz  = (const float*)d_in[7];
  const float* Lr  = (const float*)d_in[8];
  const float* Lh  = (const float*)d_in[9];
  const float* bz  = (const float*)d_in[10];
  const float* br  = (const float*)d_in[11];
  const float* bh  = (const float*)d_in[12];
  char* ws = (char*)d_ws;
  // ws layout (bytes):
  u8*  xht  = (u8*)(ws);                           // [3072][4096] fp8: 12,582,912
  u8*  adj8 = (u8*)(ws + (size_t)12582912);        // [4096][4096] fp8: 16,777,216
  u16* Mm   = (u16*)(ws + (size_t)29360128);       // [4096][3072] bf16: 25,165,824
  u16* wct  = (u16*)(ws + (size_t)54525952);       // 24 KB
  u16* lbt  = (u16*)(ws + (size_t)54550528);       // 24 KB
  float* outp = (float*)d_out;

  hipLaunchKernelGGL(kpre, dim3(5683), dim3(256), 0, stream,
                     adj, adj8, fcw, fcb, x, xht, Wz, Wr, Wh, Lz, Lr, Lh, wct, lbt);
  hipLaunchKernelGGL(k2, dim3(16, 32), dim3(256), 0, stream, adj8, xht, Mm);
  hipLaunchKernelGGL(k3, dim3(256), dim3(256), 0, stream, Mm, wct, lbt, bz, br, bh, outp);
}